// Round 1
// baseline (286.068 us; speedup 1.0000x reference)
//
#include <hip/hip_runtime.h>
#include <hip/hip_bf16.h>

#define HEADS 4
#define KCL 4
#define NBUCK 256
#define BCAP 4096            // bucket capacity (mean 3125, +17 sigma)
#define EPT 8                // edges per thread in k_bin
typedef unsigned long long u64;
typedef short short8 __attribute__((ext_vector_type(8)));
typedef float f32x4 __attribute__((ext_vector_type(4)));

__device__ __forceinline__ unsigned short bf16_rne(float f) {
    unsigned int u = __float_as_uint(f);
    u += 0x7FFFu + ((u >> 16) & 1u);
    return (unsigned short)(u >> 16);
}
__device__ __forceinline__ float bf16_to_f32(unsigned short h) {
    return __uint_as_float(((unsigned int)h) << 16);
}

// packed edge: [ea:32][dstlo:8][src:24]

// ---------------------------------------------------------------- k_bin: pass 1 — coarse-bucket append
__global__ __launch_bounds__(256) void k_bin(const int* __restrict__ src, const int* __restrict__ dst,
                                             const float* __restrict__ ea,
                                             unsigned int* __restrict__ gtail,
                                             u64* __restrict__ gbuck, int E_, int BW) {
    __shared__ unsigned int cnt[NBUCK];
    __shared__ unsigned int gb[NBUCK];
    int t = threadIdx.x;
    cnt[t] = 0u;
    __syncthreads();
    int e0 = blockIdx.x * (256 * EPT) + t;
    u64 pk[EPT]; int bk[EPT]; unsigned int ls[EPT];
    int m = 0;
#pragma unroll
    for (int i = 0; i < EPT; i++) {
        int e = e0 + i * 256;
        if (e < E_) {
            int s = src[e], d = dst[e];
            float a = ea[e];
            int b = d / BW;
            int lo = d - b * BW;
            pk[m] = ((u64)__float_as_uint(a) << 32) | ((u64)(unsigned int)lo << 24) | (unsigned int)s;
            bk[m] = b;
            ls[m] = atomicAdd(&cnt[b], 1u);
            m++;
        }
    }
    __syncthreads();
    gb[t] = (cnt[t] > 0u) ? atomicAdd(&gtail[t], cnt[t]) : 0u;
    __syncthreads();
    for (int i = 0; i < m; i++) {
        unsigned int pos = gb[bk[i]] + ls[i];
        if (pos < BCAP) gbuck[(size_t)bk[i] * BCAP + pos] = pk[i];
    }
}

// ---------------------------------------------------------------- k_scatter2: pass 2 — row-pack within bucket
__global__ __launch_bounds__(256) void k_scatter2(const unsigned int* __restrict__ gtail,
                                                  const u64* __restrict__ gbuck,
                                                  u64* __restrict__ gpacked,
                                                  int2* __restrict__ idx2, int N_, int BW) {
    __shared__ unsigned int rcnt[256], pre[256], cur[256];
    int b = blockIdx.x, t = threadIdx.x;
    unsigned int n = gtail[b]; if (n > BCAP) n = BCAP;
    int r0 = b * BW;
    rcnt[t] = 0u;
    __syncthreads();
    size_t base = (size_t)b * BCAP;
    for (unsigned int pos = t; pos < n; pos += 256) {
        u64 p = gbuck[base + pos];
        int lo = (int)((p >> 24) & 0xFFu);
        atomicAdd(&rcnt[lo], 1u);
    }
    __syncthreads();
    unsigned int v = rcnt[t];
    pre[t] = v;
    __syncthreads();
    for (int off = 1; off < 256; off <<= 1) {
        unsigned int u = (t >= off) ? pre[t - off] : 0u;
        __syncthreads();
        pre[t] += u;
        __syncthreads();
    }
    unsigned int excl = pre[t] - v;
    cur[t] = excl;
    if (t < BW && r0 + t < N_) idx2[r0 + t] = make_int2((int)(base + excl), (int)v);
    __syncthreads();
    for (unsigned int pos = t; pos < n; pos += 256) {
        u64 p = gbuck[base + pos];
        int lo = (int)((p >> 24) & 0xFFu);
        unsigned int slot = atomicAdd(&cur[lo], 1u);
        gpacked[base + slot] = p;
    }
}

// ---------------------------------------------------------------- k_prep_all: ce + u + W2T + per-node prep + accumulator zeroing
__global__ __launch_bounds__(256) void k_prep_all(const float* __restrict__ x,
                                                  const float* __restrict__ W1, const float* __restrict__ W2,
                                                  const float* __restrict__ as1, const float* __restrict__ ad1,
                                                  const float* __restrict__ as2, const float* __restrict__ ad2,
                                                  const float* __restrict__ We1, const float* __restrict__ ae1,
                                                  const float* __restrict__ We2, const float* __restrict__ ae2,
                                                  float* __restrict__ ce1, float* __restrict__ ce2,
                                                  float* __restrict__ u_s, float* __restrict__ u_d,
                                                  unsigned short* __restrict__ W2T,
                                                  float* __restrict__ xpad,
                                                  float* __restrict__ al_s1, float* __restrict__ al_d1,
                                                  float* __restrict__ zsum, unsigned int* __restrict__ gtail,
                                                  int N_) {
    __shared__ float Ps_l[7][4], Pd_l[7][4];
    int t = threadIdx.x, h = t >> 6, lane = t & 63;
    for (int i = 0; i < 7; i++) {
        float a = W1[i * 256 + t];             // t = h*64+c
        float ps = a * as1[t];
        float pd = a * ad1[t];
        for (int off = 32; off; off >>= 1) {
            ps += __shfl_down(ps, off, 64);
            pd += __shfl_down(pd, off, 64);
        }
        if (lane == 0) { Ps_l[i][h] = ps; Pd_l[i][h] = pd; }
    }
    if (blockIdx.x == 0) {
        float p = We1[t] * ae1[t];
        for (int off = 32; off; off >>= 1) p += __shfl_down(p, off, 64);
        if (lane == 0) ce1[h] = p;
        if (t < 64) {
            float q = We2[t] * ae2[t];
            for (int off = 32; off; off >>= 1) q += __shfl_down(q, off, 64);
            if (t == 0) ce2[0] = q;
        }
        float us = 0.f, ud = 0.f;
        const float* wr = W2 + t * 64;
        for (int n = 0; n < 64; n++) { us += wr[n] * as2[n]; ud += wr[n] * ad2[n]; }
        u_s[t] = us; u_d[t] = ud;
    }
    if (blockIdx.x == 1) {                     // replaces two hipMemsetAsync fills
        gtail[t] = 0u;
        zsum[t] = 0.0f;                        // zsum[256] + cntK[4] + cfK[4] contiguous
        if (t < 8) zsum[256 + t] = 0.0f;
    }
    int gidx = blockIdx.x * 256 + t;
    if (gidx < 16384) {
        int nn = gidx & 63, k = gidx >> 6;
        W2T[nn * 256 + k] = bf16_rne(W2[k * 64 + nn]);
    }
    __syncthreads();
    int n = gidx;
    if (n >= N_) return;
    float xv[7];
#pragma unroll
    for (int i = 0; i < 7; i++) xv[i] = x[n * 7 + i];
    ((float4*)(xpad + (size_t)n * 8))[0] = make_float4(xv[0], xv[1], xv[2], xv[3]);
    ((float4*)(xpad + (size_t)n * 8))[1] = make_float4(xv[4], xv[5], xv[6], 0.0f);
    float4 als = make_float4(0.f, 0.f, 0.f, 0.f);
    float4 ald = make_float4(0.f, 0.f, 0.f, 0.f);
#pragma unroll
    for (int i = 0; i < 7; i++) {
        als.x += xv[i] * Ps_l[i][0]; als.y += xv[i] * Ps_l[i][1];
        als.z += xv[i] * Ps_l[i][2]; als.w += xv[i] * Ps_l[i][3];
        ald.x += xv[i] * Pd_l[i][0]; ald.y += xv[i] * Pd_l[i][1];
        ald.z += xv[i] * Pd_l[i][2]; ald.w += xv[i] * Pd_l[i][3];
    }
    ((float4*)al_s1)[n] = als;
    ((float4*)al_d1)[n] = ald;
}

// ---------------------------------------------------------------- k_agg1f: fused edge-softmax + aggregation (conv1)
// 8 lanes per dst, each lane handles all 4 heads for a strided 1/8 of the edge
// row (single gather of al_s1/xpad per edge instead of 4x per-head redundancy),
// then 3-round shfl_xor butterfly; lanes 0-3 do self-loop + write head h.
__global__ __launch_bounds__(256) void k_agg1f(const int2* __restrict__ idx2,
                                               const u64* __restrict__ gpacked,
                                               const float* __restrict__ al_s1,
                                               const float* __restrict__ al_d1,
                                               const float* __restrict__ ce1,
                                               const float* __restrict__ xpad,
                                               float* __restrict__ xacc, int N_) {
    int tid = blockIdx.x * 256 + threadIdx.x;
    int d = tid >> 3, el = tid & 7;
    if (d >= N_) return;
    int2 ix = idx2[d];
    const u64* row = gpacked + ix.x;
    int cnt = ix.y;
    float4 ald4 = ((const float4*)al_d1)[d];
    float4 ce4 = *(const float4*)ce1;
    float4 accA[4], accB[4];                   // per head: A=feat0..3, B=feat4..6 + wsum
#pragma unroll
    for (int h = 0; h < 4; h++) {
        accA[h] = make_float4(0.f, 0.f, 0.f, 0.f);
        accB[h] = make_float4(0.f, 0.f, 0.f, 0.f);
    }
    float easum = 0.0f;
#define EDGE1(J) { \
        u64 p = row[(J)]; \
        int s = (int)(p & 0xFFFFFFu); \
        float a = __uint_as_float((unsigned int)(p >> 32)); \
        easum += a; \
        float4 als = ((const float4*)al_s1)[s]; \
        const float4* xp = (const float4*)(xpad + (size_t)s * 8); \
        float4 xa = xp[0], xb = xp[1]; \
        float vh[4]; \
        vh[0] = als.x + ald4.x + a * ce4.x; \
        vh[1] = als.y + ald4.y + a * ce4.y; \
        vh[2] = als.z + ald4.z + a * ce4.z; \
        vh[3] = als.w + ald4.w + a * ce4.w; \
        _Pragma("unroll") \
        for (int h = 0; h < 4; h++) { \
            float v = vh[h]; \
            v = v > 0.f ? v : 0.2f * v; \
            float w = __expf(v); \
            accA[h].x += w * xa.x; accA[h].y += w * xa.y; \
            accA[h].z += w * xa.z; accA[h].w += w * xa.w; \
            accB[h].x += w * xb.x; accB[h].y += w * xb.y; \
            accB[h].z += w * xb.z; accB[h].w += w; \
        } }
    int j = el;
    for (; j + 8 < cnt; j += 16) { EDGE1(j); EDGE1(j + 8); }   // 2 edges in flight
    for (; j < cnt; j += 8) { EDGE1(j); }
#undef EDGE1
    // butterfly reduce over the 8 lanes of this dst
#pragma unroll
    for (int h = 0; h < 4; h++) {
#pragma unroll
        for (int off = 1; off <= 4; off <<= 1) {
            accA[h].x += __shfl_xor(accA[h].x, off, 64);
            accA[h].y += __shfl_xor(accA[h].y, off, 64);
            accA[h].z += __shfl_xor(accA[h].z, off, 64);
            accA[h].w += __shfl_xor(accA[h].w, off, 64);
            accB[h].x += __shfl_xor(accB[h].x, off, 64);
            accB[h].y += __shfl_xor(accB[h].y, off, 64);
            accB[h].z += __shfl_xor(accB[h].z, off, 64);
            accB[h].w += __shfl_xor(accB[h].w, off, 64);
        }
    }
#pragma unroll
    for (int off = 1; off <= 4; off <<= 1) easum += __shfl_xor(easum, off, 64);
    if (el >= 4) return;
    int h = el;
    float4 A = accA[0], B = accB[0];
    float aldh = ald4.x, ceh = ce4.x;
    if (h == 1) { A = accA[1]; B = accB[1]; aldh = ald4.y; ceh = ce4.y; }
    if (h == 2) { A = accA[2]; B = accB[2]; aldh = ald4.z; ceh = ce4.z; }
    if (h == 3) { A = accA[3]; B = accB[3]; aldh = ald4.w; ceh = ce4.w; }
    float4 alsd4 = ((const float4*)al_s1)[d];
    float alsh = alsd4.x;
    if (h == 1) alsh = alsd4.y;
    if (h == 2) alsh = alsd4.z;
    if (h == 3) alsh = alsd4.w;
    // self-loop: attr = mean of real incoming ea
    float a_self = easum / fmaxf((float)cnt, 1.0f);
    float v = alsh + aldh + a_self * ceh;
    v = v > 0.f ? v : 0.2f * v;
    float w = __expf(v);
    const float4* xp = (const float4*)(xpad + (size_t)d * 8);
    float4 xa = xp[0], xb = xp[1];
    A.x += w * xa.x; A.y += w * xa.y; A.z += w * xa.z; A.w += w * xa.w;
    B.x += w * xb.x; B.y += w * xb.y; B.z += w * xb.z; B.w += w;
    float* o = xacc + (size_t)d * 32 + h * 8;
    ((float4*)o)[0] = A;
    ((float4*)o)[1] = B;
}

// ---------------------------------------------------------------- k_xw2g: MFMA h1-gen + GEMM; xw2 stored as bf16
__global__ __launch_bounds__(256) void k_xw2g(const float* __restrict__ xacc,
                                              const float* __restrict__ W1,
                                              const float* __restrict__ b1,
                                              const unsigned short* __restrict__ W2T,
                                              const float* __restrict__ u_s,
                                              const float* __restrict__ u_d,
                                              unsigned short* __restrict__ xw2b,
                                              float* __restrict__ al_s2,
                                              float* __restrict__ al_d2, int N_) {
    __shared__ float Xs[16][32];
    __shared__ __align__(16) unsigned short A_lds[16][264];  // k-pad +8 breaks bank alias
    __shared__ float als_p[16], ald_p[16];
    int t = threadIdx.x;
    int m0 = blockIdx.x * 16;
    if (t < 128) {
        int r = t >> 3, off = (t & 7) * 4;
        int n = m0 + r;
        float4 v = (n < N_) ? *(const float4*)(xacc + (size_t)n * 32 + off)
                            : make_float4(0.f, 0.f, 0.f, 0.f);
        *(float4*)&Xs[r][off] = v;
    }
    __syncthreads();
    // generation: row r = t>>4, lane-k kk = t&15 (lane-coalesced W1/u/b1 loads)
    {
        int r = t >> 4;
        int kk = t & 15;
        float ps = 0.f, pd = 0.f;
#pragma unroll
        for (int h = 0; h < 4; h++) {
            float xv[7];
#pragma unroll
            for (int i = 0; i < 7; i++) xv[i] = Xs[r][h * 8 + i];
            float rw = 1.0f / (Xs[r][h * 8 + 7] + 1e-16f);
#pragma unroll
            for (int q2 = 0; q2 < 4; q2++) {
                int k = h * 64 + q2 * 16 + kk;
                float s = 0.f;
#pragma unroll
                for (int i = 0; i < 7; i++) s += xv[i] * W1[i * 256 + k];
                float v = s * rw + b1[k];
                float a = v > 0.f ? v : (__expf(v) - 1.0f);
                ps += a * u_s[k];
                pd += a * u_d[k];
                A_lds[r][k] = bf16_rne(a);
            }
        }
#pragma unroll
        for (int mdel = 1; mdel < 16; mdel <<= 1) {
            ps += __shfl_xor(ps, mdel, 64);
            pd += __shfl_xor(pd, mdel, 64);
        }
        if (kk == 0) { als_p[r] = ps; ald_p[r] = pd; }
    }
    __syncthreads();
    // MFMA: wave w covers cols w*16..w*16+15
    int w = t >> 6, lane = t & 63;
    int mm = lane & 15, quad = lane >> 4;
    int n0 = w * 16;
    f32x4 acc = {0.f, 0.f, 0.f, 0.f};
    const unsigned short* bptr = W2T + (size_t)(n0 + mm) * 256;
#pragma unroll
    for (int step = 0; step < 8; step++) {
        int kf = step * 32 + quad * 8;
        short8 af = *(const short8*)&A_lds[mm][kf];
        short8 bf = *(const short8*)&bptr[kf];
        acc = __builtin_amdgcn_mfma_f32_16x16x32_bf16(af, bf, acc, 0, 0, 0);
    }
#pragma unroll
    for (int r = 0; r < 4; r++) {
        int row = m0 + quad * 4 + r;
        if (row < N_) xw2b[(size_t)row * 64 + n0 + mm] = bf16_rne(acc[r]);
    }
    if (t < 16 && m0 + t < N_) { al_s2[m0 + t] = als_p[t]; al_d2[m0 + t] = ald_p[t]; }
}

// ---------------------------------------------------------------- k_agg2f: conv2 softmax-aggregate, bf16 gathers
// one wave per dst (12500 blocks x 4 waves); broadcast loop unrolled x4 for ILP
__global__ __launch_bounds__(256) void k_agg2f(const int2* __restrict__ idx2,
                                               const u64* __restrict__ gpacked,
                                               const float* __restrict__ al_s2,
                                               const float* __restrict__ al_d2,
                                               const float* __restrict__ ce2,
                                               const unsigned short* __restrict__ xw2b,
                                               float* __restrict__ h2, int N_) {
    int wid = threadIdx.x >> 6, lane = threadIdx.x & 63;
    int d = blockIdx.x * 4 + wid;
    if (d >= N_) return;
    int2 ix = idx2[d];
    const u64* row = gpacked + ix.x;
    int cnt = ix.y;
    float ald = al_d2[d];
    float ce = ce2[0];
    float acc = 0.0f;
    float wlane = 0.0f, alane = 0.0f;
    for (int pos = 0; pos < cnt; pos += 64) {
        int nle = min(64, cnt - pos);
        float w = 0.0f, a = 0.0f;
        int s = d;
        if (lane < nle) {
            u64 p = row[pos + lane];
            s = (int)(p & 0xFFFFFFu);
            a = __uint_as_float((unsigned int)(p >> 32));
            float v = al_s2[s] + ald + a * ce;
            v = v > 0.f ? v : 0.2f * v;
            w = __expf(v);
        }
        wlane += w;
        alane += a;
        int jj = 0;
        for (; jj + 3 < nle; jj += 4) {
            float wj0 = __uint_as_float(__builtin_amdgcn_readlane(__float_as_uint(w), jj));
            int   sj0 = __builtin_amdgcn_readlane(s, jj);
            float wj1 = __uint_as_float(__builtin_amdgcn_readlane(__float_as_uint(w), jj + 1));
            int   sj1 = __builtin_amdgcn_readlane(s, jj + 1);
            float wj2 = __uint_as_float(__builtin_amdgcn_readlane(__float_as_uint(w), jj + 2));
            int   sj2 = __builtin_amdgcn_readlane(s, jj + 2);
            float wj3 = __uint_as_float(__builtin_amdgcn_readlane(__float_as_uint(w), jj + 3));
            int   sj3 = __builtin_amdgcn_readlane(s, jj + 3);
            acc += wj0 * bf16_to_f32(xw2b[(size_t)sj0 * 64 + lane])
                 + wj1 * bf16_to_f32(xw2b[(size_t)sj1 * 64 + lane])
                 + wj2 * bf16_to_f32(xw2b[(size_t)sj2 * 64 + lane])
                 + wj3 * bf16_to_f32(xw2b[(size_t)sj3 * 64 + lane]);
        }
        for (; jj < nle; jj++) {
            float wj = __uint_as_float(__builtin_amdgcn_readlane(__float_as_uint(w), jj));
            int   sj = __builtin_amdgcn_readlane(s, jj);
            acc += wj * bf16_to_f32(xw2b[(size_t)sj * 64 + lane]);
        }
    }
    float wsum = wlane, easum = alane;
    for (int off = 32; off; off >>= 1) {
        wsum += __shfl_xor(wsum, off, 64);
        easum += __shfl_xor(easum, off, 64);
    }
    float a_self = easum / fmaxf((float)cnt, 1.0f);
    float v = al_s2[d] + ald + a_self * ce;
    v = v > 0.f ? v : 0.2f * v;
    float w = __expf(v);
    acc += w * bf16_to_f32(xw2b[(size_t)d * 64 + lane]);
    wsum += w;
    h2[(size_t)d * 64 + lane] = acc / (wsum + 1e-16f);
}

// ---------------------------------------------------------------- k_pool: cluster pooling (LDS partials, 256 blocks)
__global__ __launch_bounds__(256) void k_pool(const float* __restrict__ h2, const float* __restrict__ x,
                                              const int* __restrict__ assign,
                                              float* __restrict__ zsum, float* __restrict__ cntK,
                                              float* __restrict__ cfK, int nNodes) {
    __shared__ float lz[KCL * 64];
    __shared__ float lc[KCL];
    __shared__ float lf[KCL];
    int t = threadIdx.x;
    lz[t] = 0.0f;
    if (t < KCL) { lc[t] = 0.0f; lf[t] = 0.0f; }
    __syncthreads();
    int lane = t & 63, wid = t >> 6;
    for (int n = blockIdx.x * 4 + wid; n < nNodes; n += gridDim.x * 4) {
        int a = assign[n];
        atomicAdd(&lz[a * 64 + lane], h2[(size_t)n * 64 + lane]);
        if (lane == 0) {
            atomicAdd(&lc[a], 1.0f);
            atomicAdd(&lf[a], x[n * 7 + 6]);
        }
    }
    __syncthreads();
    atomicAdd(&zsum[t], lz[t]);
    if (t < KCL) {
        atomicAdd(&cntK[t], lc[t]);
        atomicAdd(&cfK[t], lf[t]);
    }
}

// ---------------------------------------------------------------- k_head: actor head + outputs (4 waves, one per cluster)
__global__ __launch_bounds__(256) void k_head(const float* __restrict__ zsum, const float* __restrict__ cntK,
                                              const float* __restrict__ cfK, const float* __restrict__ b2,
                                              const float* __restrict__ A1, const float* __restrict__ c1,
                                              const float* __restrict__ A2, const float* __restrict__ c2,
                                              float* __restrict__ out) {
    __shared__ float zcf[KCL][65];
    __shared__ float logits[KCL];
    int t = threadIdx.x;                       // 256
    int k = t >> 6, c = t & 63;
    float cn = cntK[k];
    float z = (cn > 0.f) ? (zsum[k * 64 + c] / fmaxf(cn, 1.0f) + b2[c]) : 0.0f;
    zcf[k][c] = z;
    out[4 + k * 64 + c] = z;                   // z_flat
    if (c == 0) zcf[k][64] = (cn > 0.f) ? (cfK[k] / fmaxf(cn, 1.0f)) : 0.0f;
    __syncthreads();
    {
        // wave k computes logits[k]: 65x64 matvec, lane j = column
        int j = c;
        float acc = 0.0f;
        for (int i = 0; i < 65; i++) acc += zcf[k][i] * A1[i * 64 + j];
        float hr = fmaxf(acc + c1[j], 0.0f);
        float contrib = hr * A2[j];
        for (int off = 32; off; off >>= 1) contrib += __shfl_down(contrib, off, 64);
        if (j == 0) logits[k] = contrib + c2[0];
    }
    __syncthreads();
    if (t == 0) {
        float m = fmaxf(fmaxf(logits[0], logits[1]), fmaxf(logits[2], logits[3]));
        float e0 = expf(logits[0] - m), e1 = expf(logits[1] - m);
        float e2 = expf(logits[2] - m), e3 = expf(logits[3] - m);
        float s = e0 + e1 + e2 + e3;
        out[0] = e0 / s; out[1] = e1 / s; out[2] = e2 / s; out[3] = e3 / s;
    }
}

extern "C" void kernel_launch(void* const* d_in, const int* in_sizes, int n_in,
                              void* d_out, int out_size, void* d_ws, size_t ws_size,
                              hipStream_t stream) {
    const float* x      = (const float*)d_in[0];
    const int*   ei     = (const int*)d_in[1];
    const float* eattr  = (const float*)d_in[2];
    const int*   assign = (const int*)d_in[3];
    const float* W1     = (const float*)d_in[4];
    const float* as1    = (const float*)d_in[5];
    const float* ad1    = (const float*)d_in[6];
    const float* We1    = (const float*)d_in[7];
    const float* ae1    = (const float*)d_in[8];
    const float* b1     = (const float*)d_in[9];
    const float* W2     = (const float*)d_in[10];
    const float* as2    = (const float*)d_in[11];
    const float* ad2    = (const float*)d_in[12];
    const float* We2    = (const float*)d_in[13];
    const float* ae2    = (const float*)d_in[14];
    const float* b2     = (const float*)d_in[15];
    const float* A1     = (const float*)d_in[16];
    const float* c1     = (const float*)d_in[17];
    const float* A2     = (const float*)d_in[18];
    const float* c2     = (const float*)d_in[19];
    float* out = (float*)d_out;

    const int N_ = in_sizes[0] / 7;            // 50000
    const int E_ = in_sizes[2];                // 800000
    const int NB = (N_ + 255) / 256;
    const int BW = (N_ + NBUCK - 1) / NBUCK;   // 196 rows per bucket
    const int* srcA = ei;
    const int* dstA = ei + E_;

    // ---- workspace layout ----
    float* ws = (float*)d_ws;
    size_t Nz = (size_t)N_;
    float* al_s1   = ws;                       // 4N
    float* al_d1   = al_s1 + 4 * Nz;           // 4N
    float* al_s2   = al_d1 + 4 * Nz;           // N
    float* al_d2   = al_s2 + Nz;               // N
    float* ce1     = al_d2 + Nz;               // 4
    float* ce2     = ce1 + 4;                  // 4 (padded)
    float* zsum    = ce2 + 4;                  // 256
    float* cntK    = zsum + 256;               // 4
    float* cfK     = cntK + 4;                 // 4
    float* u_s     = cfK + 4;                  // 256
    float* u_d     = u_s + 256;                // 256
    float* xpad    = ws + 10 * Nz + 1024;      // 8N
    float* xacc    = xpad + 8 * Nz;            // 32N
    unsigned short* xw2b = (unsigned short*)(xacc + 32 * Nz);  // 64N bf16 (= 32N floats)
    float* h2      = (float*)(xw2b + 64 * Nz); // 64N
    uintptr_t pp   = (uintptr_t)(h2 + 64 * Nz);
    u64* gbuck     = (u64*)((pp + 7) & ~(uintptr_t)7);       // NBUCK*BCAP u64 (8 MB)
    u64* gpacked   = gbuck + (size_t)NBUCK * BCAP;           // NBUCK*BCAP u64 (8 MB)
    unsigned int* gtail = (unsigned int*)(gpacked + (size_t)NBUCK * BCAP);  // 256
    int2* idx2     = (int2*)(gtail + 256);                   // N int2
    unsigned short* W2T = (unsigned short*)(idx2 + Nz);      // 64*256 bf16

    // ---- constants + transpose + node prep + accumulator zeroing (one dispatch) ----
    k_prep_all<<<NB, 256, 0, stream>>>(x, W1, W2, as1, ad1, as2, ad2,
                                       We1, ae1, We2, ae2,
                                       ce1, ce2, u_s, u_d, W2T,
                                       xpad, al_s1, al_d1, zsum, gtail, N_);

    // ---- two-pass binned CSR build (line-dense writes) ----
    k_bin<<<(E_ + 256 * EPT - 1) / (256 * EPT), 256, 0, stream>>>(srcA, dstA, eattr, gtail, gbuck, E_, BW);
    k_scatter2<<<NBUCK, 256, 0, stream>>>(gtail, gbuck, gpacked, idx2, N_, BW);

    // ---- conv1: 8 lanes per dst, all heads per lane ----
    k_agg1f<<<(8 * N_ + 255) / 256, 256, 0, stream>>>(idx2, gpacked, al_s1, al_d1, ce1, xpad, xacc, N_);

    // ---- conv2: MFMA h1-gen + GEMM (bf16 out), softmax-aggregate (1 wave/dst), pooling ----
    k_xw2g<<<(N_ + 15) / 16, 256, 0, stream>>>(xacc, W1, b1, W2T, u_s, u_d,
                                               xw2b, al_s2, al_d2, N_);
    k_agg2f<<<(N_ + 3) / 4, 256, 0, stream>>>(idx2, gpacked, al_s2, al_d2, ce2, xw2b, h2, N_);
    k_pool<<<256, 256, 0, stream>>>(h2, x, assign, zsum, cntK, cfK, N_);

    // ---- head ----
    k_head<<<1, 256, 0, stream>>>(zsum, cntK, cfK, b2, A1, c1, A2, c2, out);
}

// Round 2
// 258.216 us; speedup vs baseline: 1.1079x; 1.1079x over previous
//
#include <hip/hip_runtime.h>
#include <hip/hip_bf16.h>

#define HEADS 4
#define KCL 4
#define NBUCK 256
#define BCAP 4096            // bucket capacity (mean 3125, +17 sigma)
#define EPT 8                // edges per thread in k_bin
typedef unsigned long long u64;
typedef short short8 __attribute__((ext_vector_type(8)));
typedef float f32x4 __attribute__((ext_vector_type(4)));

__device__ __forceinline__ unsigned short bf16_rne(float f) {
    unsigned int u = __float_as_uint(f);
    u += 0x7FFFu + ((u >> 16) & 1u);
    return (unsigned short)(u >> 16);
}
__device__ __forceinline__ float bf16_to_f32(unsigned short h) {
    return __uint_as_float(((unsigned int)h) << 16);
}

// packed edge: [ea:32][dstlo:8][src:24]
// node record nrec[n][16]: [0:4)=al_s1 (4 heads), [4:8)=al_d1, [8:15)=x, [15]=0  (64B aligned line)

// ---------------------------------------------------------------- k_bin: pass 1 — coarse-bucket append
__global__ __launch_bounds__(256) void k_bin(const int* __restrict__ src, const int* __restrict__ dst,
                                             const float* __restrict__ ea,
                                             unsigned int* __restrict__ gtail,
                                             u64* __restrict__ gbuck, int E_, int BW) {
    __shared__ unsigned int cnt[NBUCK];
    __shared__ unsigned int gb[NBUCK];
    int t = threadIdx.x;
    cnt[t] = 0u;
    __syncthreads();
    int e0 = blockIdx.x * (256 * EPT) + t;
    u64 pk[EPT]; int bk[EPT]; unsigned int ls[EPT];
    int m = 0;
#pragma unroll
    for (int i = 0; i < EPT; i++) {
        int e = e0 + i * 256;
        if (e < E_) {
            int s = src[e], d = dst[e];
            float a = ea[e];
            int b = d / BW;
            int lo = d - b * BW;
            pk[m] = ((u64)__float_as_uint(a) << 32) | ((u64)(unsigned int)lo << 24) | (unsigned int)s;
            bk[m] = b;
            ls[m] = atomicAdd(&cnt[b], 1u);
            m++;
        }
    }
    __syncthreads();
    gb[t] = (cnt[t] > 0u) ? atomicAdd(&gtail[t], cnt[t]) : 0u;
    __syncthreads();
    for (int i = 0; i < m; i++) {
        unsigned int pos = gb[bk[i]] + ls[i];
        if (pos < BCAP) gbuck[(size_t)bk[i] * BCAP + pos] = pk[i];
    }
}

// ---------------------------------------------------------------- k_scatter2: pass 2 — row-pack within bucket
__global__ __launch_bounds__(256) void k_scatter2(const unsigned int* __restrict__ gtail,
                                                  const u64* __restrict__ gbuck,
                                                  u64* __restrict__ gpacked,
                                                  int2* __restrict__ idx2, int N_, int BW) {
    __shared__ unsigned int rcnt[256], pre[256], cur[256];
    int b = blockIdx.x, t = threadIdx.x;
    unsigned int n = gtail[b]; if (n > BCAP) n = BCAP;
    int r0 = b * BW;
    rcnt[t] = 0u;
    __syncthreads();
    size_t base = (size_t)b * BCAP;
    for (unsigned int pos = t; pos < n; pos += 256) {
        u64 p = gbuck[base + pos];
        int lo = (int)((p >> 24) & 0xFFu);
        atomicAdd(&rcnt[lo], 1u);
    }
    __syncthreads();
    unsigned int v = rcnt[t];
    pre[t] = v;
    __syncthreads();
    for (int off = 1; off < 256; off <<= 1) {
        unsigned int u = (t >= off) ? pre[t - off] : 0u;
        __syncthreads();
        pre[t] += u;
        __syncthreads();
    }
    unsigned int excl = pre[t] - v;
    cur[t] = excl;
    if (t < BW && r0 + t < N_) idx2[r0 + t] = make_int2((int)(base + excl), (int)v);
    __syncthreads();
    for (unsigned int pos = t; pos < n; pos += 256) {
        u64 p = gbuck[base + pos];
        int lo = (int)((p >> 24) & 0xFFu);
        unsigned int slot = atomicAdd(&cur[lo], 1u);
        gpacked[base + slot] = p;
    }
}

// ---------------------------------------------------------------- k_prep_all: ce + u + W2T + node records + accumulator zeroing
__global__ __launch_bounds__(256) void k_prep_all(const float* __restrict__ x,
                                                  const float* __restrict__ W1, const float* __restrict__ W2,
                                                  const float* __restrict__ as1, const float* __restrict__ ad1,
                                                  const float* __restrict__ as2, const float* __restrict__ ad2,
                                                  const float* __restrict__ We1, const float* __restrict__ ae1,
                                                  const float* __restrict__ We2, const float* __restrict__ ae2,
                                                  float* __restrict__ ce1, float* __restrict__ ce2,
                                                  float* __restrict__ u_s, float* __restrict__ u_d,
                                                  unsigned short* __restrict__ W2T,
                                                  float* __restrict__ nrec,
                                                  float* __restrict__ zsum, unsigned int* __restrict__ gtail,
                                                  int N_) {
    __shared__ float Ps_l[7][4], Pd_l[7][4];
    int t = threadIdx.x, h = t >> 6, lane = t & 63;
    for (int i = 0; i < 7; i++) {
        float a = W1[i * 256 + t];             // t = h*64+c
        float ps = a * as1[t];
        float pd = a * ad1[t];
        for (int off = 32; off; off >>= 1) {
            ps += __shfl_down(ps, off, 64);
            pd += __shfl_down(pd, off, 64);
        }
        if (lane == 0) { Ps_l[i][h] = ps; Pd_l[i][h] = pd; }
    }
    if (blockIdx.x == 0) {
        float p = We1[t] * ae1[t];
        for (int off = 32; off; off >>= 1) p += __shfl_down(p, off, 64);
        if (lane == 0) ce1[h] = p;
        if (t < 64) {
            float q = We2[t] * ae2[t];
            for (int off = 32; off; off >>= 1) q += __shfl_down(q, off, 64);
            if (t == 0) ce2[0] = q;
        }
        float us = 0.f, ud = 0.f;
        const float* wr = W2 + t * 64;
        for (int n = 0; n < 64; n++) { us += wr[n] * as2[n]; ud += wr[n] * ad2[n]; }
        u_s[t] = us; u_d[t] = ud;
    }
    if (blockIdx.x == 1) {                     // replaces two hipMemsetAsync fills
        gtail[t] = 0u;
        zsum[t] = 0.0f;                        // zsum[256] + cntK[4] + cfK[4] contiguous
        if (t < 8) zsum[256 + t] = 0.0f;
    }
    int gidx = blockIdx.x * 256 + t;
    if (gidx < 16384) {
        int nn = gidx & 63, k = gidx >> 6;
        W2T[nn * 256 + k] = bf16_rne(W2[k * 64 + nn]);
    }
    __syncthreads();
    int n = gidx;
    if (n >= N_) return;
    float xv[7];
#pragma unroll
    for (int i = 0; i < 7; i++) xv[i] = x[n * 7 + i];
    float4 als = make_float4(0.f, 0.f, 0.f, 0.f);
    float4 ald = make_float4(0.f, 0.f, 0.f, 0.f);
#pragma unroll
    for (int i = 0; i < 7; i++) {
        als.x += xv[i] * Ps_l[i][0]; als.y += xv[i] * Ps_l[i][1];
        als.z += xv[i] * Ps_l[i][2]; als.w += xv[i] * Ps_l[i][3];
        ald.x += xv[i] * Pd_l[i][0]; ald.y += xv[i] * Pd_l[i][1];
        ald.z += xv[i] * Pd_l[i][2]; ald.w += xv[i] * Pd_l[i][3];
    }
    float4* nr = (float4*)(nrec + (size_t)n * 16);
    nr[0] = als;
    nr[1] = ald;
    nr[2] = make_float4(xv[0], xv[1], xv[2], xv[3]);
    nr[3] = make_float4(xv[4], xv[5], xv[6], 0.0f);
}

// ---------------------------------------------------------------- k_agg1f: fused edge-softmax + aggregation (conv1)
// thread = (dst, head, half): 400k threads = 6250 waves. Per edge, the gather
// (als scalar + 2x float4 of x) hits exactly ONE 64B line of nrec. Halves
// combine with a single shfl_xor round (9 values). Edge stream loaded nt.
__global__ __launch_bounds__(256) void k_agg1f(const int2* __restrict__ idx2,
                                               const u64* __restrict__ gpacked,
                                               const float* __restrict__ nrec,
                                               const float* __restrict__ ce1,
                                               float* __restrict__ xacc, int N_) {
    int tid = blockIdx.x * 256 + threadIdx.x;
    int d = tid >> 3;
    if (d >= N_) return;
    int sub = tid & 7, h = sub >> 1, half = sub & 1;
    int2 ix = idx2[d];
    const u64* row = gpacked + ix.x;
    int cnt = ix.y;
    const float* nd = nrec + (size_t)d * 16;
    float ald = nd[4 + h];
    float ce = ce1[h];
    float4 A = make_float4(0.f, 0.f, 0.f, 0.f);
    float4 B = make_float4(0.f, 0.f, 0.f, 0.f);   // .w = wsum
    float easum = 0.0f;
#define E1(J) { \
        u64 p = __builtin_nontemporal_load(&row[(J)]); \
        int s = (int)(p & 0xFFFFFFu); \
        float a = __uint_as_float((unsigned int)(p >> 32)); \
        const float* ns = nrec + (size_t)s * 16; \
        float als = ns[h]; \
        float4 xa = *(const float4*)(ns + 8); \
        float4 xb = *(const float4*)(ns + 12); \
        easum += a; \
        float v = als + ald + a * ce; \
        v = v > 0.f ? v : 0.2f * v; \
        float w = __expf(v); \
        A.x += w * xa.x; A.y += w * xa.y; A.z += w * xa.z; A.w += w * xa.w; \
        B.x += w * xb.x; B.y += w * xb.y; B.z += w * xb.z; B.w += w; }
    int j = half;
    for (; j + 6 < cnt; j += 8) { E1(j); E1(j + 2); E1(j + 4); E1(j + 6); }   // 4 edges in flight
    for (; j < cnt; j += 2) { E1(j); }
#undef E1
    // combine the two halves (single xor round)
    A.x += __shfl_xor(A.x, 1, 64);
    A.y += __shfl_xor(A.y, 1, 64);
    A.z += __shfl_xor(A.z, 1, 64);
    A.w += __shfl_xor(A.w, 1, 64);
    B.x += __shfl_xor(B.x, 1, 64);
    B.y += __shfl_xor(B.y, 1, 64);
    B.z += __shfl_xor(B.z, 1, 64);
    B.w += __shfl_xor(B.w, 1, 64);
    easum += __shfl_xor(easum, 1, 64);
    if (half) return;
    // self-loop: attr = mean of real incoming ea
    float a_self = easum / fmaxf((float)cnt, 1.0f);
    float v = nd[h] + ald + a_self * ce;
    v = v > 0.f ? v : 0.2f * v;
    float w = __expf(v);
    float4 xa = *(const float4*)(nd + 8);
    float4 xb = *(const float4*)(nd + 12);
    A.x += w * xa.x; A.y += w * xa.y; A.z += w * xa.z; A.w += w * xa.w;
    B.x += w * xb.x; B.y += w * xb.y; B.z += w * xb.z; B.w += w;
    float* o = xacc + (size_t)d * 32 + h * 8;
    ((float4*)o)[0] = A;
    ((float4*)o)[1] = B;
}

// ---------------------------------------------------------------- k_xw2g: MFMA h1-gen + GEMM; xw2 stored as bf16
__global__ __launch_bounds__(256) void k_xw2g(const float* __restrict__ xacc,
                                              const float* __restrict__ W1,
                                              const float* __restrict__ b1,
                                              const unsigned short* __restrict__ W2T,
                                              const float* __restrict__ u_s,
                                              const float* __restrict__ u_d,
                                              unsigned short* __restrict__ xw2b,
                                              float* __restrict__ al_s2,
                                              float* __restrict__ al_d2, int N_) {
    __shared__ float Xs[16][32];
    __shared__ __align__(16) unsigned short A_lds[16][264];  // k-pad +8 breaks bank alias
    __shared__ float als_p[16], ald_p[16];
    int t = threadIdx.x;
    int m0 = blockIdx.x * 16;
    if (t < 128) {
        int r = t >> 3, off = (t & 7) * 4;
        int n = m0 + r;
        float4 v = (n < N_) ? *(const float4*)(xacc + (size_t)n * 32 + off)
                            : make_float4(0.f, 0.f, 0.f, 0.f);
        *(float4*)&Xs[r][off] = v;
    }
    __syncthreads();
    // generation: row r = t>>4, lane-k kk = t&15 (lane-coalesced W1/u/b1 loads)
    {
        int r = t >> 4;
        int kk = t & 15;
        float ps = 0.f, pd = 0.f;
#pragma unroll
        for (int h = 0; h < 4; h++) {
            float xv[7];
#pragma unroll
            for (int i = 0; i < 7; i++) xv[i] = Xs[r][h * 8 + i];
            float rw = 1.0f / (Xs[r][h * 8 + 7] + 1e-16f);
#pragma unroll
            for (int q2 = 0; q2 < 4; q2++) {
                int k = h * 64 + q2 * 16 + kk;
                float s = 0.f;
#pragma unroll
                for (int i = 0; i < 7; i++) s += xv[i] * W1[i * 256 + k];
                float v = s * rw + b1[k];
                float a = v > 0.f ? v : (__expf(v) - 1.0f);
                ps += a * u_s[k];
                pd += a * u_d[k];
                A_lds[r][k] = bf16_rne(a);
            }
        }
#pragma unroll
        for (int mdel = 1; mdel < 16; mdel <<= 1) {
            ps += __shfl_xor(ps, mdel, 64);
            pd += __shfl_xor(pd, mdel, 64);
        }
        if (kk == 0) { als_p[r] = ps; ald_p[r] = pd; }
    }
    __syncthreads();
    // MFMA: wave w covers cols w*16..w*16+15
    int w = t >> 6, lane = t & 63;
    int mm = lane & 15, quad = lane >> 4;
    int n0 = w * 16;
    f32x4 acc = {0.f, 0.f, 0.f, 0.f};
    const unsigned short* bptr = W2T + (size_t)(n0 + mm) * 256;
#pragma unroll
    for (int step = 0; step < 8; step++) {
        int kf = step * 32 + quad * 8;
        short8 af = *(const short8*)&A_lds[mm][kf];
        short8 bf = *(const short8*)&bptr[kf];
        acc = __builtin_amdgcn_mfma_f32_16x16x32_bf16(af, bf, acc, 0, 0, 0);
    }
#pragma unroll
    for (int r = 0; r < 4; r++) {
        int row = m0 + quad * 4 + r;
        if (row < N_) xw2b[(size_t)row * 64 + n0 + mm] = bf16_rne(acc[r]);
    }
    if (t < 16 && m0 + t < N_) { al_s2[m0 + t] = als_p[t]; al_d2[m0 + t] = ald_p[t]; }
}

// ---------------------------------------------------------------- k_agg2f: conv2 softmax-aggregate, bf16 gathers
// one wave per dst (12500 blocks x 4 waves); broadcast loop unrolled x4 for ILP
__global__ __launch_bounds__(256) void k_agg2f(const int2* __restrict__ idx2,
                                               const u64* __restrict__ gpacked,
                                               const float* __restrict__ al_s2,
                                               const float* __restrict__ al_d2,
                                               const float* __restrict__ ce2,
                                               const unsigned short* __restrict__ xw2b,
                                               float* __restrict__ h2, int N_) {
    int wid = threadIdx.x >> 6, lane = threadIdx.x & 63;
    int d = blockIdx.x * 4 + wid;
    if (d >= N_) return;
    int2 ix = idx2[d];
    const u64* row = gpacked + ix.x;
    int cnt = ix.y;
    float ald = al_d2[d];
    float ce = ce2[0];
    float acc = 0.0f;
    float wlane = 0.0f, alane = 0.0f;
    for (int pos = 0; pos < cnt; pos += 64) {
        int nle = min(64, cnt - pos);
        float w = 0.0f, a = 0.0f;
        int s = d;
        if (lane < nle) {
            u64 p = __builtin_nontemporal_load(&row[pos + lane]);
            s = (int)(p & 0xFFFFFFu);
            a = __uint_as_float((unsigned int)(p >> 32));
            float v = al_s2[s] + ald + a * ce;
            v = v > 0.f ? v : 0.2f * v;
            w = __expf(v);
        }
        wlane += w;
        alane += a;
        int jj = 0;
        for (; jj + 3 < nle; jj += 4) {
            float wj0 = __uint_as_float(__builtin_amdgcn_readlane(__float_as_uint(w), jj));
            int   sj0 = __builtin_amdgcn_readlane(s, jj);
            float wj1 = __uint_as_float(__builtin_amdgcn_readlane(__float_as_uint(w), jj + 1));
            int   sj1 = __builtin_amdgcn_readlane(s, jj + 1);
            float wj2 = __uint_as_float(__builtin_amdgcn_readlane(__float_as_uint(w), jj + 2));
            int   sj2 = __builtin_amdgcn_readlane(s, jj + 2);
            float wj3 = __uint_as_float(__builtin_amdgcn_readlane(__float_as_uint(w), jj + 3));
            int   sj3 = __builtin_amdgcn_readlane(s, jj + 3);
            acc += wj0 * bf16_to_f32(xw2b[(size_t)sj0 * 64 + lane])
                 + wj1 * bf16_to_f32(xw2b[(size_t)sj1 * 64 + lane])
                 + wj2 * bf16_to_f32(xw2b[(size_t)sj2 * 64 + lane])
                 + wj3 * bf16_to_f32(xw2b[(size_t)sj3 * 64 + lane]);
        }
        for (; jj < nle; jj++) {
            float wj = __uint_as_float(__builtin_amdgcn_readlane(__float_as_uint(w), jj));
            int   sj = __builtin_amdgcn_readlane(s, jj);
            acc += wj * bf16_to_f32(xw2b[(size_t)sj * 64 + lane]);
        }
    }
    float wsum = wlane, easum = alane;
    for (int off = 32; off; off >>= 1) {
        wsum += __shfl_xor(wsum, off, 64);
        easum += __shfl_xor(easum, off, 64);
    }
    float a_self = easum / fmaxf((float)cnt, 1.0f);
    float v = al_s2[d] + ald + a_self * ce;
    v = v > 0.f ? v : 0.2f * v;
    float w = __expf(v);
    acc += w * bf16_to_f32(xw2b[(size_t)d * 64 + lane]);
    wsum += w;
    h2[(size_t)d * 64 + lane] = acc / (wsum + 1e-16f);
}

// ---------------------------------------------------------------- k_pool: cluster pooling (LDS partials, 256 blocks)
__global__ __launch_bounds__(256) void k_pool(const float* __restrict__ h2, const float* __restrict__ x,
                                              const int* __restrict__ assign,
                                              float* __restrict__ zsum, float* __restrict__ cntK,
                                              float* __restrict__ cfK, int nNodes) {
    __shared__ float lz[KCL * 64];
    __shared__ float lc[KCL];
    __shared__ float lf[KCL];
    int t = threadIdx.x;
    lz[t] = 0.0f;
    if (t < KCL) { lc[t] = 0.0f; lf[t] = 0.0f; }
    __syncthreads();
    int lane = t & 63, wid = t >> 6;
    for (int n = blockIdx.x * 4 + wid; n < nNodes; n += gridDim.x * 4) {
        int a = assign[n];
        atomicAdd(&lz[a * 64 + lane], h2[(size_t)n * 64 + lane]);
        if (lane == 0) {
            atomicAdd(&lc[a], 1.0f);
            atomicAdd(&lf[a], x[n * 7 + 6]);
        }
    }
    __syncthreads();
    atomicAdd(&zsum[t], lz[t]);
    if (t < KCL) {
        atomicAdd(&cntK[t], lc[t]);
        atomicAdd(&cfK[t], lf[t]);
    }
}

// ---------------------------------------------------------------- k_head: actor head + outputs (4 waves, one per cluster)
__global__ __launch_bounds__(256) void k_head(const float* __restrict__ zsum, const float* __restrict__ cntK,
                                              const float* __restrict__ cfK, const float* __restrict__ b2,
                                              const float* __restrict__ A1, const float* __restrict__ c1,
                                              const float* __restrict__ A2, const float* __restrict__ c2,
                                              float* __restrict__ out) {
    __shared__ float zcf[KCL][65];
    __shared__ float logits[KCL];
    int t = threadIdx.x;                       // 256
    int k = t >> 6, c = t & 63;
    float cn = cntK[k];
    float z = (cn > 0.f) ? (zsum[k * 64 + c] / fmaxf(cn, 1.0f) + b2[c]) : 0.0f;
    zcf[k][c] = z;
    out[4 + k * 64 + c] = z;                   // z_flat
    if (c == 0) zcf[k][64] = (cn > 0.f) ? (cfK[k] / fmaxf(cn, 1.0f)) : 0.0f;
    __syncthreads();
    {
        // wave k computes logits[k]: 65x64 matvec, lane j = column
        int j = c;
        float acc = 0.0f;
        for (int i = 0; i < 65; i++) acc += zcf[k][i] * A1[i * 64 + j];
        float hr = fmaxf(acc + c1[j], 0.0f);
        float contrib = hr * A2[j];
        for (int off = 32; off; off >>= 1) contrib += __shfl_down(contrib, off, 64);
        if (j == 0) logits[k] = contrib + c2[0];
    }
    __syncthreads();
    if (t == 0) {
        float m = fmaxf(fmaxf(logits[0], logits[1]), fmaxf(logits[2], logits[3]));
        float e0 = expf(logits[0] - m), e1 = expf(logits[1] - m);
        float e2 = expf(logits[2] - m), e3 = expf(logits[3] - m);
        float s = e0 + e1 + e2 + e3;
        out[0] = e0 / s; out[1] = e1 / s; out[2] = e2 / s; out[3] = e3 / s;
    }
}

extern "C" void kernel_launch(void* const* d_in, const int* in_sizes, int n_in,
                              void* d_out, int out_size, void* d_ws, size_t ws_size,
                              hipStream_t stream) {
    const float* x      = (const float*)d_in[0];
    const int*   ei     = (const int*)d_in[1];
    const float* eattr  = (const float*)d_in[2];
    const int*   assign = (const int*)d_in[3];
    const float* W1     = (const float*)d_in[4];
    const float* as1    = (const float*)d_in[5];
    const float* ad1    = (const float*)d_in[6];
    const float* We1    = (const float*)d_in[7];
    const float* ae1    = (const float*)d_in[8];
    const float* b1     = (const float*)d_in[9];
    const float* W2     = (const float*)d_in[10];
    const float* as2    = (const float*)d_in[11];
    const float* ad2    = (const float*)d_in[12];
    const float* We2    = (const float*)d_in[13];
    const float* ae2    = (const float*)d_in[14];
    const float* b2     = (const float*)d_in[15];
    const float* A1     = (const float*)d_in[16];
    const float* c1     = (const float*)d_in[17];
    const float* A2     = (const float*)d_in[18];
    const float* c2     = (const float*)d_in[19];
    float* out = (float*)d_out;

    const int N_ = in_sizes[0] / 7;            // 50000
    const int E_ = in_sizes[2];                // 800000
    const int NB = (N_ + 255) / 256;
    const int BW = (N_ + NBUCK - 1) / NBUCK;   // 196 rows per bucket
    const int* srcA = ei;
    const int* dstA = ei + E_;

    // ---- workspace layout ----
    float* ws = (float*)d_ws;
    size_t Nz = (size_t)N_;
    float* nrec    = ws;                       // 16N (64B-aligned node records)
    float* al_s2   = nrec + 16 * Nz;           // N
    float* al_d2   = al_s2 + Nz;               // N
    float* ce1     = al_d2 + Nz;               // 4
    float* ce2     = ce1 + 4;                  // 4 (padded)
    float* zsum    = ce2 + 4;                  // 256
    float* cntK    = zsum + 256;               // 4
    float* cfK     = cntK + 4;                 // 4
    float* u_s     = cfK + 4;                  // 256
    float* u_d     = u_s + 256;                // 256
    float* xacc    = ws + 18 * Nz + 1024;      // 32N
    unsigned short* xw2b = (unsigned short*)(xacc + 32 * Nz);  // 64N bf16 (= 32N floats)
    float* h2      = (float*)(xw2b + 64 * Nz); // 64N
    uintptr_t pp   = (uintptr_t)(h2 + 64 * Nz);
    u64* gbuck     = (u64*)((pp + 7) & ~(uintptr_t)7);       // NBUCK*BCAP u64 (8 MB)
    u64* gpacked   = gbuck + (size_t)NBUCK * BCAP;           // NBUCK*BCAP u64 (8 MB)
    unsigned int* gtail = (unsigned int*)(gpacked + (size_t)NBUCK * BCAP);  // 256
    int2* idx2     = (int2*)(gtail + 256);                   // N int2
    unsigned short* W2T = (unsigned short*)(idx2 + Nz);      // 64*256 bf16

    // ---- constants + transpose + node records + accumulator zeroing (one dispatch) ----
    k_prep_all<<<NB, 256, 0, stream>>>(x, W1, W2, as1, ad1, as2, ad2,
                                       We1, ae1, We2, ae2,
                                       ce1, ce2, u_s, u_d, W2T,
                                       nrec, zsum, gtail, N_);

    // ---- two-pass binned CSR build (line-dense writes) ----
    k_bin<<<(E_ + 256 * EPT - 1) / (256 * EPT), 256, 0, stream>>>(srcA, dstA, eattr, gtail, gbuck, E_, BW);
    k_scatter2<<<NBUCK, 256, 0, stream>>>(gtail, gbuck, gpacked, idx2, N_, BW);

    // ---- conv1: (dst, head, half) threads, single-line gathers ----
    k_agg1f<<<(8 * N_ + 255) / 256, 256, 0, stream>>>(idx2, gpacked, nrec, ce1, xacc, N_);

    // ---- conv2: MFMA h1-gen + GEMM (bf16 out), softmax-aggregate (1 wave/dst), pooling ----
    k_xw2g<<<(N_ + 15) / 16, 256, 0, stream>>>(xacc, W1, b1, W2T, u_s, u_d,
                                               xw2b, al_s2, al_d2, N_);
    k_agg2f<<<(N_ + 3) / 4, 256, 0, stream>>>(idx2, gpacked, al_s2, al_d2, ce2, xw2b, h2, N_);
    k_pool<<<256, 256, 0, stream>>>(h2, x, assign, zsum, cntK, cfK, N_);

    // ---- head ----
    k_head<<<1, 256, 0, stream>>>(zsum, cntK, cfK, b2, A1, c1, A2, c2, out);
}

// Round 3
// 240.674 us; speedup vs baseline: 1.1886x; 1.0729x over previous
//
#include <hip/hip_runtime.h>
#include <hip/hip_bf16.h>

#define HEADS 4
#define KCL 4
#define BSHIFT 7
#define BW 128               // bucket width (pow2: shift/and instead of div)
#define NBUCKMAX 400         // >= (50000+127)/128 = 391
#define BCAP 2560            // bucket capacity (mean 2048, +11 sigma)
#define EPT 8                // edges per thread in bin phase
typedef unsigned long long u64;
typedef short short8 __attribute__((ext_vector_type(8)));
typedef float f32x4 __attribute__((ext_vector_type(4)));

__device__ __forceinline__ unsigned short bf16_rne(float f) {
    unsigned int u = __float_as_uint(f);
    u += 0x7FFFu + ((u >> 16) & 1u);
    return (unsigned short)(u >> 16);
}
__device__ __forceinline__ float bf16_to_f32(unsigned short h) {
    return __uint_as_float(((unsigned int)h) << 16);
}

// packed edge: [ea:32][dstlo:8][src:24]
// node record nrec[n][16]: [0:4)=al_s1 (4 heads), [4:8)=al_d1, [8:15)=x, [15]=0  (64B line)

// ---------------------------------------------------------------- k_prep_bin: fused prep (blocks [0,NB)) + edge binning (blocks [NB, NB+NBBIN))
__global__ __launch_bounds__(256) void k_prep_bin(const float* __restrict__ x,
                                                  const float* __restrict__ W1, const float* __restrict__ W2,
                                                  const float* __restrict__ as1, const float* __restrict__ ad1,
                                                  const float* __restrict__ as2, const float* __restrict__ ad2,
                                                  const float* __restrict__ We1, const float* __restrict__ ae1,
                                                  const float* __restrict__ We2, const float* __restrict__ ae2,
                                                  float* __restrict__ ce1, float* __restrict__ ce2,
                                                  float* __restrict__ u_s, float* __restrict__ u_d,
                                                  unsigned short* __restrict__ W2T,
                                                  float* __restrict__ nrec,
                                                  const int* __restrict__ src, const int* __restrict__ dst,
                                                  const float* __restrict__ ea,
                                                  unsigned int* __restrict__ gtail,
                                                  u64* __restrict__ gbuck,
                                                  int N_, int E_, int NB, int nbuck) {
    int t = threadIdx.x;
    if ((int)blockIdx.x >= NB) {
        // ---------------- bin path ----------------
        __shared__ unsigned int cnt[NBUCKMAX];
        __shared__ unsigned int gb[NBUCKMAX];
        for (int i = t; i < nbuck; i += 256) cnt[i] = 0u;
        __syncthreads();
        int bid = blockIdx.x - NB;
        int e0 = bid * (256 * EPT) + t;
        u64 pk[EPT]; int bk[EPT]; unsigned int ls[EPT];
#pragma unroll
        for (int i = 0; i < EPT; i++) {            // static indices only (no scratch)
            int e = e0 + i * 256;
            bool valid = e < E_;
            int s = 0, d = 0; float a = 0.0f;
            if (valid) { s = src[e]; d = dst[e]; a = ea[e]; }
            int b = d >> BSHIFT;
            int lo = d & (BW - 1);
            pk[i] = ((u64)__float_as_uint(a) << 32) | ((u64)(unsigned int)lo << 24) | (unsigned int)s;
            bk[i] = b;
            ls[i] = valid ? atomicAdd(&cnt[b], 1u) : 0u;
        }
        __syncthreads();
        for (int i = t; i < nbuck; i += 256)
            gb[i] = (cnt[i] > 0u) ? atomicAdd(&gtail[i], cnt[i]) : 0u;
        __syncthreads();
#pragma unroll
        for (int i = 0; i < EPT; i++) {
            if (e0 + i * 256 < E_) {
                unsigned int pos = gb[bk[i]] + ls[i];
                if (pos < BCAP) gbuck[(size_t)bk[i] * BCAP + pos] = pk[i];
            }
        }
        return;
    }
    // ---------------- prep path ----------------
    __shared__ float Ps_l[7][4], Pd_l[7][4];
    int h = t >> 6, lane = t & 63;
    for (int i = 0; i < 7; i++) {
        float a = W1[i * 256 + t];             // t = h*64+c
        float ps = a * as1[t];
        float pd = a * ad1[t];
        for (int off = 32; off; off >>= 1) {
            ps += __shfl_down(ps, off, 64);
            pd += __shfl_down(pd, off, 64);
        }
        if (lane == 0) { Ps_l[i][h] = ps; Pd_l[i][h] = pd; }
    }
    if (blockIdx.x == 0) {
        float p = We1[t] * ae1[t];
        for (int off = 32; off; off >>= 1) p += __shfl_down(p, off, 64);
        if (lane == 0) ce1[h] = p;
        if (t < 64) {
            float q = We2[t] * ae2[t];
            for (int off = 32; off; off >>= 1) q += __shfl_down(q, off, 64);
            if (t == 0) ce2[0] = q;
        }
        float us = 0.f, ud = 0.f;
        const float* wr = W2 + t * 64;
        for (int n = 0; n < 64; n++) { us += wr[n] * as2[n]; ud += wr[n] * ad2[n]; }
        u_s[t] = us; u_d[t] = ud;
    }
    int gidx = blockIdx.x * 256 + t;
    if (gidx < 16384) {
        int nn = gidx & 63, k = gidx >> 6;
        W2T[nn * 256 + k] = bf16_rne(W2[k * 64 + nn]);
    }
    __syncthreads();
    int n = gidx;
    if (n >= N_) return;
    float xv[7];
#pragma unroll
    for (int i = 0; i < 7; i++) xv[i] = x[n * 7 + i];
    float4 als = make_float4(0.f, 0.f, 0.f, 0.f);
    float4 ald = make_float4(0.f, 0.f, 0.f, 0.f);
#pragma unroll
    for (int i = 0; i < 7; i++) {
        als.x += xv[i] * Ps_l[i][0]; als.y += xv[i] * Ps_l[i][1];
        als.z += xv[i] * Ps_l[i][2]; als.w += xv[i] * Ps_l[i][3];
        ald.x += xv[i] * Pd_l[i][0]; ald.y += xv[i] * Pd_l[i][1];
        ald.z += xv[i] * Pd_l[i][2]; ald.w += xv[i] * Pd_l[i][3];
    }
    float4* nr = (float4*)(nrec + (size_t)n * 16);
    nr[0] = als;
    nr[1] = ald;
    nr[2] = make_float4(xv[0], xv[1], xv[2], xv[3]);
    nr[3] = make_float4(xv[4], xv[5], xv[6], 0.0f);
}

// ---------------------------------------------------------------- k_scatter2: row-pack within bucket (391 blocks)
__global__ __launch_bounds__(256) void k_scatter2(const unsigned int* __restrict__ gtail,
                                                  const u64* __restrict__ gbuck,
                                                  u64* __restrict__ gpacked,
                                                  int2* __restrict__ idx2, int N_) {
    __shared__ unsigned int rcnt[256], pre[256], cur[256];
    int b = blockIdx.x, t = threadIdx.x;
    unsigned int n = gtail[b]; if (n > BCAP) n = BCAP;
    int r0 = b << BSHIFT;
    rcnt[t] = 0u;
    __syncthreads();
    size_t base = (size_t)b * BCAP;
    for (unsigned int pos = t; pos < n; pos += 256) {
        u64 p = gbuck[base + pos];
        int lo = (int)((p >> 24) & 0xFFu);
        atomicAdd(&rcnt[lo], 1u);
    }
    __syncthreads();
    unsigned int v = rcnt[t];
    pre[t] = v;
    __syncthreads();
    for (int off = 1; off < 256; off <<= 1) {
        unsigned int u = (t >= off) ? pre[t - off] : 0u;
        __syncthreads();
        pre[t] += u;
        __syncthreads();
    }
    unsigned int excl = pre[t] - v;
    cur[t] = excl;
    if (t < BW && r0 + t < N_) idx2[r0 + t] = make_int2((int)(base + excl), (int)v);
    __syncthreads();
    for (unsigned int pos = t; pos < n; pos += 256) {
        u64 p = gbuck[base + pos];
        int lo = (int)((p >> 24) & 0xFFu);
        unsigned int slot = atomicAdd(&cur[lo], 1u);
        gpacked[base + slot] = p;
    }
}

// ---------------------------------------------------------------- k_agg1_xw2g: fused conv1 aggregate + h1-gen + MFMA GEMM
// Phase A: 32 dsts/block, 8 lanes/dst = (head, half); single-line nrec gathers;
//          results land in LDS Xs2 (no xacc global roundtrip).
// Phase B: h1 generation (ELU + al2 partials) into A_lds as bf16.
// Phase C: 16x16x32 bf16 MFMA, 2 row-tiles per wave, xw2b out.
__global__ __launch_bounds__(256) void k_agg1_xw2g(const int2* __restrict__ idx2,
                                                   const u64* __restrict__ gpacked,
                                                   const float* __restrict__ nrec,
                                                   const float* __restrict__ ce1,
                                                   const float* __restrict__ W1,
                                                   const float* __restrict__ b1,
                                                   const unsigned short* __restrict__ W2T,
                                                   const float* __restrict__ u_s,
                                                   const float* __restrict__ u_d,
                                                   unsigned short* __restrict__ xw2b,
                                                   float* __restrict__ al_s2,
                                                   float* __restrict__ al_d2, int N_) {
    __shared__ float Xs2[32][36];              // stride 36: 16B-aligned rows, banks spread
    __shared__ __align__(16) unsigned short A_lds[32][264];  // k-pad +8 breaks bank alias
    __shared__ float als_p[32], ald_p[32];
    int t = threadIdx.x;
    int m0 = blockIdx.x * 32;
    // -------- Phase A: conv1 aggregation --------
    {
        int dl = t >> 3, d = m0 + dl;
        int sub = t & 7, h = sub >> 1, half = sub & 1;
        bool act = d < N_;
        float4 A = make_float4(0.f, 0.f, 0.f, 0.f);
        float4 B = make_float4(0.f, 0.f, 0.f, 0.f);   // .w = wsum
        if (act) {
            int2 ix = idx2[d];
            const u64* row = gpacked + ix.x;
            int cnt = ix.y;
            const float* nd = nrec + (size_t)d * 16;
            float ald = nd[4 + h];
            float ce = ce1[h];
            float easum = 0.0f;
#define E1(J) { \
            u64 p = __builtin_nontemporal_load(&row[(J)]); \
            int s = (int)(p & 0xFFFFFFu); \
            float a = __uint_as_float((unsigned int)(p >> 32)); \
            const float* ns = nrec + (size_t)s * 16; \
            float als = ns[h]; \
            float4 xa = *(const float4*)(ns + 8); \
            float4 xb = *(const float4*)(ns + 12); \
            easum += a; \
            float v = als + ald + a * ce; \
            v = v > 0.f ? v : 0.2f * v; \
            float w = __expf(v); \
            A.x += w * xa.x; A.y += w * xa.y; A.z += w * xa.z; A.w += w * xa.w; \
            B.x += w * xb.x; B.y += w * xb.y; B.z += w * xb.z; B.w += w; }
            int j = half;
            for (; j + 6 < cnt; j += 8) { E1(j); E1(j + 2); E1(j + 4); E1(j + 6); }
            for (; j < cnt; j += 2) { E1(j); }
#undef E1
            // combine halves (xor partner is within the same 8-lane group)
            A.x += __shfl_xor(A.x, 1, 64);
            A.y += __shfl_xor(A.y, 1, 64);
            A.z += __shfl_xor(A.z, 1, 64);
            A.w += __shfl_xor(A.w, 1, 64);
            B.x += __shfl_xor(B.x, 1, 64);
            B.y += __shfl_xor(B.y, 1, 64);
            B.z += __shfl_xor(B.z, 1, 64);
            B.w += __shfl_xor(B.w, 1, 64);
            easum += __shfl_xor(easum, 1, 64);
            if (!half) {
                // self-loop: attr = mean of real incoming ea
                float a_self = easum / fmaxf((float)cnt, 1.0f);
                float v = nd[h] + ald + a_self * ce;
                v = v > 0.f ? v : 0.2f * v;
                float w = __expf(v);
                float4 xa = *(const float4*)(nd + 8);
                float4 xb = *(const float4*)(nd + 12);
                A.x += w * xa.x; A.y += w * xa.y; A.z += w * xa.z; A.w += w * xa.w;
                B.x += w * xb.x; B.y += w * xb.y; B.z += w * xb.z; B.w += w;
            }
        }
        if (!half) {                            // inactive rows write zeros
            *(float4*)&Xs2[dl][h * 8] = A;
            *(float4*)&Xs2[dl][h * 8 + 4] = B;
        }
    }
    __syncthreads();
    // -------- Phase B: h1 generation; row r = t>>3, kk = t&7 --------
    {
        int r = t >> 3;
        int kk = t & 7;
        float ps = 0.f, pd = 0.f;
#pragma unroll
        for (int hh = 0; hh < 4; hh++) {
            float xv[7];
#pragma unroll
            for (int i = 0; i < 7; i++) xv[i] = Xs2[r][hh * 8 + i];
            float rw = 1.0f / (Xs2[r][hh * 8 + 7] + 1e-16f);
#pragma unroll
            for (int q = 0; q < 8; q++) {
                int k = hh * 64 + q * 8 + kk;
                float s = 0.f;
#pragma unroll
                for (int i = 0; i < 7; i++) s += xv[i] * W1[i * 256 + k];
                float v = s * rw + b1[k];
                float a = v > 0.f ? v : (__expf(v) - 1.0f);
                ps += a * u_s[k];
                pd += a * u_d[k];
                A_lds[r][k] = bf16_rne(a);
            }
        }
        ps += __shfl_xor(ps, 1, 64); pd += __shfl_xor(pd, 1, 64);
        ps += __shfl_xor(ps, 2, 64); pd += __shfl_xor(pd, 2, 64);
        ps += __shfl_xor(ps, 4, 64); pd += __shfl_xor(pd, 4, 64);
        if (kk == 0) { als_p[r] = ps; ald_p[r] = pd; }
    }
    __syncthreads();
    // -------- Phase C: MFMA; wave w covers cols w*16..w*16+15, rows 0..15 & 16..31 --------
    {
        int w = t >> 6, lane = t & 63;
        int mm = lane & 15, quad = lane >> 4;
        int n0 = w * 16;
        f32x4 acc0 = {0.f, 0.f, 0.f, 0.f};
        f32x4 acc1 = {0.f, 0.f, 0.f, 0.f};
        const unsigned short* bptr = W2T + (size_t)(n0 + mm) * 256;
#pragma unroll
        for (int step = 0; step < 8; step++) {
            int kf = step * 32 + quad * 8;
            short8 bf = *(const short8*)&bptr[kf];
            short8 af0 = *(const short8*)&A_lds[mm][kf];
            short8 af1 = *(const short8*)&A_lds[16 + mm][kf];
            acc0 = __builtin_amdgcn_mfma_f32_16x16x32_bf16(af0, bf, acc0, 0, 0, 0);
            acc1 = __builtin_amdgcn_mfma_f32_16x16x32_bf16(af1, bf, acc1, 0, 0, 0);
        }
#pragma unroll
        for (int r = 0; r < 4; r++) {
            int row0 = m0 + quad * 4 + r;
            if (row0 < N_) xw2b[(size_t)row0 * 64 + n0 + mm] = bf16_rne(acc0[r]);
            int row1 = row0 + 16;
            if (row1 < N_) xw2b[(size_t)row1 * 64 + n0 + mm] = bf16_rne(acc1[r]);
        }
    }
    if (t < 32 && m0 + t < N_) { al_s2[m0 + t] = als_p[t]; al_d2[m0 + t] = ald_p[t]; }
}

// ---------------------------------------------------------------- k_agg2f: conv2 softmax-aggregate, bf16 gathers
// one wave per dst (12500 blocks x 4 waves); broadcast loop unrolled x8 for MLP
__global__ __launch_bounds__(256) void k_agg2f(const int2* __restrict__ idx2,
                                               const u64* __restrict__ gpacked,
                                               const float* __restrict__ al_s2,
                                               const float* __restrict__ al_d2,
                                               const float* __restrict__ ce2,
                                               const unsigned short* __restrict__ xw2b,
                                               float* __restrict__ h2, int N_) {
    int wid = threadIdx.x >> 6, lane = threadIdx.x & 63;
    int d = blockIdx.x * 4 + wid;
    if (d >= N_) return;
    int2 ix = idx2[d];
    const u64* row = gpacked + ix.x;
    int cnt = ix.y;
    float ald = al_d2[d];
    float ce = ce2[0];
    float acc = 0.0f;
    float wlane = 0.0f, alane = 0.0f;
    for (int pos = 0; pos < cnt; pos += 64) {
        int nle = min(64, cnt - pos);
        float w = 0.0f, a = 0.0f;
        int s = d;
        if (lane < nle) {
            u64 p = __builtin_nontemporal_load(&row[pos + lane]);
            s = (int)(p & 0xFFFFFFu);
            a = __uint_as_float((unsigned int)(p >> 32));
            float v = al_s2[s] + ald + a * ce;
            v = v > 0.f ? v : 0.2f * v;
            w = __expf(v);
        }
        wlane += w;
        alane += a;
        int jj = 0;
#define G1(OFS) \
        float w##OFS = __uint_as_float(__builtin_amdgcn_readlane(__float_as_uint(w), jj + OFS)); \
        int   s##OFS = __builtin_amdgcn_readlane(s, jj + OFS);
        for (; jj + 7 < nle; jj += 8) {
            G1(0) G1(1) G1(2) G1(3) G1(4) G1(5) G1(6) G1(7)
            acc += w0 * bf16_to_f32(xw2b[(size_t)s0 * 64 + lane])
                 + w1 * bf16_to_f32(xw2b[(size_t)s1 * 64 + lane])
                 + w2 * bf16_to_f32(xw2b[(size_t)s2 * 64 + lane])
                 + w3 * bf16_to_f32(xw2b[(size_t)s3 * 64 + lane])
                 + w4 * bf16_to_f32(xw2b[(size_t)s4 * 64 + lane])
                 + w5 * bf16_to_f32(xw2b[(size_t)s5 * 64 + lane])
                 + w6 * bf16_to_f32(xw2b[(size_t)s6 * 64 + lane])
                 + w7 * bf16_to_f32(xw2b[(size_t)s7 * 64 + lane]);
        }
        for (; jj < nle; jj++) {
            G1(0)
            acc += w0 * bf16_to_f32(xw2b[(size_t)s0 * 64 + lane]);
        }
#undef G1
    }
    float wsum = wlane, easum = alane;
    for (int off = 32; off; off >>= 1) {
        wsum += __shfl_xor(wsum, off, 64);
        easum += __shfl_xor(easum, off, 64);
    }
    float a_self = easum / fmaxf((float)cnt, 1.0f);
    float v = al_s2[d] + ald + a_self * ce;
    v = v > 0.f ? v : 0.2f * v;
    float w = __expf(v);
    acc += w * bf16_to_f32(xw2b[(size_t)d * 64 + lane]);
    wsum += w;
    h2[(size_t)d * 64 + lane] = acc / (wsum + 1e-16f);
}

// ---------------------------------------------------------------- k_pool: cluster pooling (LDS partials, 256 blocks)
__global__ __launch_bounds__(256) void k_pool(const float* __restrict__ h2, const float* __restrict__ x,
                                              const int* __restrict__ assign,
                                              float* __restrict__ zsum, float* __restrict__ cntK,
                                              float* __restrict__ cfK, int nNodes) {
    __shared__ float lz[KCL * 64];
    __shared__ float lc[KCL];
    __shared__ float lf[KCL];
    int t = threadIdx.x;
    lz[t] = 0.0f;
    if (t < KCL) { lc[t] = 0.0f; lf[t] = 0.0f; }
    __syncthreads();
    int lane = t & 63, wid = t >> 6;
    for (int n = blockIdx.x * 4 + wid; n < nNodes; n += gridDim.x * 4) {
        int a = assign[n];
        atomicAdd(&lz[a * 64 + lane], h2[(size_t)n * 64 + lane]);
        if (lane == 0) {
            atomicAdd(&lc[a], 1.0f);
            atomicAdd(&lf[a], x[n * 7 + 6]);
        }
    }
    __syncthreads();
    atomicAdd(&zsum[t], lz[t]);
    if (t < KCL) {
        atomicAdd(&cntK[t], lc[t]);
        atomicAdd(&cfK[t], lf[t]);
    }
}

// ---------------------------------------------------------------- k_head: actor head + outputs (4 waves, one per cluster)
__global__ __launch_bounds__(256) void k_head(const float* __restrict__ zsum, const float* __restrict__ cntK,
                                              const float* __restrict__ cfK, const float* __restrict__ b2,
                                              const float* __restrict__ A1, const float* __restrict__ c1,
                                              const float* __restrict__ A2, const float* __restrict__ c2,
                                              float* __restrict__ out) {
    __shared__ float zcf[KCL][65];
    __shared__ float logits[KCL];
    int t = threadIdx.x;                       // 256
    int k = t >> 6, c = t & 63;
    float cn = cntK[k];
    float z = (cn > 0.f) ? (zsum[k * 64 + c] / fmaxf(cn, 1.0f) + b2[c]) : 0.0f;
    zcf[k][c] = z;
    out[4 + k * 64 + c] = z;                   // z_flat
    if (c == 0) zcf[k][64] = (cn > 0.f) ? (cfK[k] / fmaxf(cn, 1.0f)) : 0.0f;
    __syncthreads();
    {
        // wave k computes logits[k]: 65x64 matvec, lane j = column
        int j = c;
        float acc = 0.0f;
        for (int i = 0; i < 65; i++) acc += zcf[k][i] * A1[i * 64 + j];
        float hr = fmaxf(acc + c1[j], 0.0f);
        float contrib = hr * A2[j];
        for (int off = 32; off; off >>= 1) contrib += __shfl_down(contrib, off, 64);
        if (j == 0) logits[k] = contrib + c2[0];
    }
    __syncthreads();
    if (t == 0) {
        float m = fmaxf(fmaxf(logits[0], logits[1]), fmaxf(logits[2], logits[3]));
        float e0 = expf(logits[0] - m), e1 = expf(logits[1] - m);
        float e2 = expf(logits[2] - m), e3 = expf(logits[3] - m);
        float s = e0 + e1 + e2 + e3;
        out[0] = e0 / s; out[1] = e1 / s; out[2] = e2 / s; out[3] = e3 / s;
    }
}

extern "C" void kernel_launch(void* const* d_in, const int* in_sizes, int n_in,
                              void* d_out, int out_size, void* d_ws, size_t ws_size,
                              hipStream_t stream) {
    const float* x      = (const float*)d_in[0];
    const int*   ei     = (const int*)d_in[1];
    const float* eattr  = (const float*)d_in[2];
    const int*   assign = (const int*)d_in[3];
    const float* W1     = (const float*)d_in[4];
    const float* as1    = (const float*)d_in[5];
    const float* ad1    = (const float*)d_in[6];
    const float* We1    = (const float*)d_in[7];
    const float* ae1    = (const float*)d_in[8];
    const float* b1     = (const float*)d_in[9];
    const float* W2     = (const float*)d_in[10];
    const float* as2    = (const float*)d_in[11];
    const float* ad2    = (const float*)d_in[12];
    const float* We2    = (const float*)d_in[13];
    const float* ae2    = (const float*)d_in[14];
    const float* b2     = (const float*)d_in[15];
    const float* A1     = (const float*)d_in[16];
    const float* c1     = (const float*)d_in[17];
    const float* A2     = (const float*)d_in[18];
    const float* c2     = (const float*)d_in[19];
    float* out = (float*)d_out;

    const int N_ = in_sizes[0] / 7;            // 50000
    const int E_ = in_sizes[2];                // 800000
    const int NB = (N_ + 255) / 256;           // 196
    const int nbuck = (N_ + BW - 1) >> BSHIFT; // 391
    const int NBBIN = (E_ + 256 * EPT - 1) / (256 * EPT);  // 391
    const int* srcA = ei;
    const int* dstA = ei + E_;

    // ---- workspace layout ----
    float* ws = (float*)d_ws;
    size_t Nz = (size_t)N_;
    float* nrec    = ws;                       // 16N (64B-aligned node records)
    float* al_s2   = nrec + 16 * Nz;           // N
    float* al_d2   = al_s2 + Nz;               // N
    float* ce1     = al_d2 + Nz;               // 4
    float* ce2     = ce1 + 4;                  // 4 (padded)
    float* zsum    = ce2 + 4;                  // 256  ┐
    float* cntK    = zsum + 256;               // 4    │ one contiguous memset
    float* cfK     = cntK + 4;                 // 4    │ region (656 x 4B)
    unsigned int* gtail = (unsigned int*)(cfK + 4);          // 392 ┘
    float* u_s     = (float*)(gtail + 392);    // 256
    float* u_d     = u_s + 256;                // 256
    unsigned short* xw2b = (unsigned short*)(u_d + 256);     // 64N bf16 (= 32N floats)
    float* h2      = (float*)(xw2b + 64 * Nz); // 64N
    uintptr_t pp   = (uintptr_t)(h2 + 64 * Nz);
    u64* gbuck     = (u64*)((pp + 7) & ~(uintptr_t)7);       // nbuck*BCAP u64 (~8 MB)
    u64* gpacked   = gbuck + (size_t)nbuck * BCAP;           // nbuck*BCAP u64 (~8 MB)
    int2* idx2     = (int2*)(gpacked + (size_t)nbuck * BCAP);  // N int2
    unsigned short* W2T = (unsigned short*)(idx2 + Nz);      // 64*256 bf16

    // ---- zero accumulators + bucket tails (one fill) ----
    hipMemsetAsync(zsum, 0, (264 + 392) * sizeof(float), stream);

    // ---- fused prep (196 blocks) || edge binning (391 blocks) ----
    k_prep_bin<<<NB + NBBIN, 256, 0, stream>>>(x, W1, W2, as1, ad1, as2, ad2,
                                               We1, ae1, We2, ae2,
                                               ce1, ce2, u_s, u_d, W2T, nrec,
                                               srcA, dstA, eattr, gtail, gbuck,
                                               N_, E_, NB, nbuck);

    // ---- pass 2: row-pack within bucket ----
    k_scatter2<<<nbuck, 256, 0, stream>>>(gtail, gbuck, gpacked, idx2, N_);

    // ---- conv1 aggregate + h1 generation + MFMA GEMM (fused, 32 rows/block) ----
    k_agg1_xw2g<<<(N_ + 31) / 32, 256, 0, stream>>>(idx2, gpacked, nrec, ce1,
                                                    W1, b1, W2T, u_s, u_d,
                                                    xw2b, al_s2, al_d2, N_);

    // ---- conv2 softmax-aggregate (1 wave/dst), pooling ----
    k_agg2f<<<(N_ + 3) / 4, 256, 0, stream>>>(idx2, gpacked, al_s2, al_d2, ce2, xw2b, h2, N_);
    k_pool<<<256, 256, 0, stream>>>(h2, x, assign, zsum, cntK, cfK, N_);

    // ---- head ----
    k_head<<<1, 256, 0, stream>>>(zsum, cntK, cfK, b2, A1, c1, A2, c2, out);
}